// Round 1
// baseline (420.084 us; speedup 1.0000x reference)
//
#include <hip/hip_runtime.h>

// out[b, l, :] = x[b, perm[b, l], :]
// B=64, L=4096, D=256 (fp32). One wave (64 lanes) per output row:
// lane i moves float4 #i of the 64 float4s in the row (256 floats).
// Both load and store are contiguous 1 KiB per wave.

#define B_DIM 64
#define L_DIM 4096
#define D_DIM 256
#define D4    (D_DIM / 4)   // 64 float4 per row == one per lane

__global__ __launch_bounds__(256) void gather_rows_kernel(
    const float4* __restrict__ x,
    const int*    __restrict__ perm,
    float4*       __restrict__ out)
{
    // 4 waves per block, one row per wave
    const int wave_in_block = threadIdx.x >> 6;   // 0..3
    const int lane          = threadIdx.x & 63;   // 0..63
    const int row           = blockIdx.x * 4 + wave_in_block;  // 0..B*L-1

    const int b = row >> 12;          // row / L_DIM
    // perm index for this row (wave-uniform load, broadcast from cache)
    const int src = perm[row];

    const long out_off = (long)row * D4 + lane;
    const long in_off  = ((long)b * L_DIM + (long)src) * D4 + lane;

    out[out_off] = x[in_off];
}

extern "C" void kernel_launch(void* const* d_in, const int* in_sizes, int n_in,
                              void* d_out, int out_size, void* d_ws, size_t ws_size,
                              hipStream_t stream) {
    const float4* x    = (const float4*)d_in[0];
    const int*    perm = (const int*)d_in[1];
    float4*       out  = (float4*)d_out;

    const int total_rows = B_DIM * L_DIM;          // 262144
    const int blocks     = total_rows / 4;         // 4 rows per 256-thread block

    gather_rows_kernel<<<blocks, 256, 0, stream>>>(x, perm, out);
}